// Round 2
// baseline (370.426 us; speedup 1.0000x reference)
//
#include <hip/hip_runtime.h>

// GAT layer for MI355X. Pipeline:
//  1. proj_kernel : xh = x @ Wl  (+ alpha_l/alpha_r in epilogue via LDS atomics)
//  2. count/scan/fill : build CSR by destination node (exp(leakyrelu) stored in CSR order)
//  3. agg_kernel  : one wave per node, gather-accumulate, normalize, coalesced write
//  4. out_kernel  : out = agg @ Wout + bias
// Softmax max-subtraction skipped (shift-invariant; logits bounded ~|6|).

#define NEG_SLOPE 0.2f

// ---------------- GEMM1: [N,128] x [128,128] + alpha epilogue ----------------
__global__ __launch_bounds__(256) void proj_kernel(
    const float* __restrict__ x, const float* __restrict__ Wl,
    const float* __restrict__ attL, const float* __restrict__ attR,
    float* __restrict__ xh, float* __restrict__ AL, float* __restrict__ AR)
{
    __shared__ float Ws[128 * 128];   // 64 KB
    __shared__ float xst[128 * 20];   // transposed x tile [k][r], pad 20 (16B-aligned rows)
    __shared__ float al_s[32];
    __shared__ float ar_s[32];
    const int tid = threadIdx.x;
    const int row0 = blockIdx.x * 16;

    // stage W (float4, coalesced)
    const float4* W4 = (const float4*)Wl;
    float4* Ws4 = (float4*)Ws;
#pragma unroll
    for (int it = 0; it < 16; ++it) Ws4[it * 256 + tid] = W4[it * 256 + tid];
    // stage x tile transposed
    const float4* x4 = (const float4*)x;
#pragma unroll
    for (int it = 0; it < 2; ++it) {
        int f4 = it * 256 + tid;          // [0,512)
        int r = f4 >> 5, kq = f4 & 31;
        float4 v = x4[(size_t)(row0 + r) * 32 + kq];
        int k0 = kq * 4;
        xst[(k0 + 0) * 20 + r] = v.x;
        xst[(k0 + 1) * 20 + r] = v.y;
        xst[(k0 + 2) * 20 + r] = v.z;
        xst[(k0 + 3) * 20 + r] = v.w;
    }
    if (tid < 32) { al_s[tid] = 0.f; ar_s[tid] = 0.f; }
    __syncthreads();

    const int cg = tid & 63;   // 64 col-groups x 2 cols
    const int rg = tid >> 6;   // 4 row-groups x 4 rows
    const int c0 = cg * 2, r0 = rg * 4;
    float acc[4][2] = {};
#pragma unroll 4
    for (int k = 0; k < 128; ++k) {
        float4 xv = *(const float4*)&xst[k * 20 + r0];
        float2 wv = *(const float2*)&Ws[k * 128 + c0];
        acc[0][0] += xv.x * wv.x; acc[0][1] += xv.x * wv.y;
        acc[1][0] += xv.y * wv.x; acc[1][1] += xv.y * wv.y;
        acc[2][0] += xv.z * wv.x; acc[2][1] += xv.z * wv.y;
        acc[3][0] += xv.w * wv.x; acc[3][1] += xv.w * wv.y;
    }
    const float aL0 = attL[c0], aL1 = attL[c0 + 1];
    const float aR0 = attR[c0], aR1 = attR[c0 + 1];
    const int head = cg >> 5;
#pragma unroll
    for (int i = 0; i < 4; ++i) {
        int row = row0 + r0 + i;
        *(float2*)&xh[(size_t)row * 128 + c0] = make_float2(acc[i][0], acc[i][1]);
        float pl = acc[i][0] * aL0 + acc[i][1] * aL1;
        float pr = acc[i][0] * aR0 + acc[i][1] * aR1;
        atomicAdd(&al_s[(r0 + i) * 2 + head], pl);
        atomicAdd(&ar_s[(r0 + i) * 2 + head], pr);
    }
    __syncthreads();
    if (tid < 32) {
        AL[row0 * 2 + tid] = al_s[tid];
        AR[row0 * 2 + tid] = ar_s[tid];
    }
}

// ---------------- CSR build ----------------
__global__ void count_kernel(const int* __restrict__ ei, int E, int Etot,
                             int* __restrict__ cnt)
{
    int e = blockIdx.x * 256 + threadIdx.x;
    if (e >= Etot) return;
    int dst = (e < E) ? ei[E + e] : (e - E);
    atomicAdd(&cnt[dst], 1);
}

__global__ __launch_bounds__(256) void scan1(const int* __restrict__ cnt, int N,
                                             int* __restrict__ off, int* __restrict__ chs)
{
    __shared__ int s[256];
    int t = threadIdx.x, i = blockIdx.x * 256 + t;
    int v = (i < N) ? cnt[i] : 0;
    s[t] = v; __syncthreads();
#pragma unroll
    for (int o = 1; o < 256; o <<= 1) {
        int add = (t >= o) ? s[t - o] : 0;
        __syncthreads();
        s[t] += add;
        __syncthreads();
    }
    if (i < N) off[i] = s[t] - v;           // exclusive within chunk
    if (t == 255) chs[blockIdx.x] = s[255]; // chunk total
}

__global__ __launch_bounds__(256) void scan2(int* __restrict__ chs, int nb)
{
    __shared__ int s[256];
    int t = threadIdx.x;
    int v = (t < nb) ? chs[t] : 0;
    s[t] = v; __syncthreads();
#pragma unroll
    for (int o = 1; o < 256; o <<= 1) {
        int add = (t >= o) ? s[t - o] : 0;
        __syncthreads();
        s[t] += add;
        __syncthreads();
    }
    if (t < nb) chs[t] = s[t] - v;          // exclusive chunk offsets
}

__global__ void scan3(int* __restrict__ off, const int* __restrict__ chs, int N)
{
    int i = blockIdx.x * 256 + threadIdx.x;
    if (i < N) off[i] += chs[i >> 8];
}

__global__ void fill_kernel(const int* __restrict__ ei, int E, int Etot,
                            const float* __restrict__ AL, const float* __restrict__ AR,
                            int* __restrict__ off, int* __restrict__ srcs,
                            float* __restrict__ exs)
{
    int e = blockIdx.x * 256 + threadIdx.x;
    if (e >= Etot) return;
    int src, dst;
    if (e < E) { src = ei[e]; dst = ei[E + e]; }
    else       { src = e - E; dst = e - E; }
    float e0 = AL[src * 2]     + AR[dst * 2];
    float e1 = AL[src * 2 + 1] + AR[dst * 2 + 1];
    e0 = (e0 < 0.f) ? NEG_SLOPE * e0 : e0;
    e1 = (e1 < 0.f) ? NEG_SLOPE * e1 : e1;
    float x0 = expf(e0), x1 = expf(e1);
    int pos = atomicAdd(&off[dst], 1);      // off becomes "end" after this pass
    srcs[pos] = src;
    *(float2*)&exs[2 * pos] = make_float2(x0, x1);
}

// ---------------- aggregation: one wave per node ----------------
__global__ __launch_bounds__(256) void agg_kernel(
    const int* __restrict__ off, const int* __restrict__ cnt,
    const int* __restrict__ srcs, const float* __restrict__ exs,
    const float* __restrict__ xh, float* __restrict__ agg, int N)
{
    int wid = threadIdx.x >> 6, lane = threadIdx.x & 63;
    int node = blockIdx.x * 4 + wid;
    if (node >= N) return;
    int end = off[node];            // post-fill: start + deg
    int deg = cnt[node];
    int start = end - deg;
    int head = lane >> 5;           // channels 0..63 head0, 64..127 head1
    int c = lane * 2;
    float a0 = 0.f, a1 = 0.f, wsum = 0.f;
    for (int e = start; e < end; ++e) {
        int j = srcs[e];
        float w = exs[2 * e + head];
        float2 v = *(const float2*)&xh[(size_t)j * 128 + c];
        a0 += w * v.x; a1 += w * v.y; wsum += w;
    }
    float inv = 1.f / (wsum + 1e-16f);
    *(float2*)&agg[(size_t)node * 128 + c] = make_float2(a0 * inv, a1 * inv);
}

// ---------------- GEMM2: [N,128] x [128,64] + bias ----------------
__global__ __launch_bounds__(256) void out_kernel(
    const float* __restrict__ agg, const float* __restrict__ Wout,
    const float* __restrict__ bias, float* __restrict__ out)
{
    __shared__ float Ws[128 * 64];  // 32 KB
    __shared__ float xst[128 * 20];
    int tid = threadIdx.x;
    int row0 = blockIdx.x * 16;
    const float4* W4 = (const float4*)Wout;
    float4* Ws4 = (float4*)Ws;
#pragma unroll
    for (int it = 0; it < 8; ++it) Ws4[it * 256 + tid] = W4[it * 256 + tid];
    const float4* a4 = (const float4*)agg;
#pragma unroll
    for (int it = 0; it < 2; ++it) {
        int f4 = it * 256 + tid;
        int r = f4 >> 5, kq = f4 & 31;
        float4 v = a4[(size_t)(row0 + r) * 32 + kq];
        int k0 = kq * 4;
        xst[(k0 + 0) * 20 + r] = v.x;
        xst[(k0 + 1) * 20 + r] = v.y;
        xst[(k0 + 2) * 20 + r] = v.z;
        xst[(k0 + 3) * 20 + r] = v.w;
    }
    __syncthreads();
    int c0 = tid & 63;              // one col each
    int rg = tid >> 6; int r0 = rg * 4;
    float acc[4] = {};
#pragma unroll 4
    for (int k = 0; k < 128; ++k) {
        float4 xv = *(const float4*)&xst[k * 20 + r0];
        float wv = Ws[k * 64 + c0];
        acc[0] += xv.x * wv; acc[1] += xv.y * wv;
        acc[2] += xv.z * wv; acc[3] += xv.w * wv;
    }
    float b = bias[c0];
#pragma unroll
    for (int i = 0; i < 4; ++i)
        out[(size_t)(row0 + r0 + i) * 64 + c0] = acc[i] + b;
}

// ---------------- launch ----------------
extern "C" void kernel_launch(void* const* d_in, const int* in_sizes, int n_in,
                              void* d_out, int out_size, void* d_ws, size_t ws_size,
                              hipStream_t stream)
{
    const float* x    = (const float*)d_in[0];
    const int*   ei   = (const int*)d_in[1];   // [2,E] int32
    const float* Wl   = (const float*)d_in[2];
    const float* attL = (const float*)d_in[3];
    const float* attR = (const float*)d_in[4];
    const float* Wout = (const float*)d_in[5];
    const float* bias = (const float*)d_in[6];
    float* out = (float*)d_out;

    const int N = in_sizes[0] / 128;   // 50000
    const int E = in_sizes[1] / 2;     // 800000
    const int Etot = E + N;            // +self-loops

    char* ws = (char*)d_ws;
    size_t o = 0;
    auto alloc = [&](size_t bytes) {
        void* p = ws + o; o += (bytes + 255) & ~(size_t)255; return p;
    };
    float* XH  = (float*)alloc((size_t)N * 128 * 4);   // 25.6 MB
    float* AL  = (float*)alloc((size_t)N * 2 * 4);
    float* AR  = (float*)alloc((size_t)N * 2 * 4);
    int*   CNT = (int*)  alloc((size_t)N * 4);
    int*   OFF = (int*)  alloc((size_t)N * 4);
    int*   CHS = (int*)  alloc(256 * 4);
    int*   SRCS= (int*)  alloc((size_t)Etot * 4);
    float* EXS = (float*)alloc((size_t)Etot * 2 * 4);
    float* AGG = (float*)alloc((size_t)N * 128 * 4);   // 25.6 MB

    hipMemsetAsync(CNT, 0, (size_t)N * 4, stream);

    proj_kernel<<<N / 16, 256, 0, stream>>>(x, Wl, attL, attR, XH, AL, AR);

    int eb = (Etot + 255) / 256;
    count_kernel<<<eb, 256, 0, stream>>>(ei, E, Etot, CNT);

    int nb = (N + 255) / 256;   // 196 <= 256
    scan1<<<nb, 256, 0, stream>>>(CNT, N, OFF, CHS);
    scan2<<<1, 256, 0, stream>>>(CHS, nb);
    scan3<<<nb, 256, 0, stream>>>(OFF, CHS, N);

    fill_kernel<<<eb, 256, 0, stream>>>(ei, E, Etot, AL, AR, OFF, SRCS, EXS);

    agg_kernel<<<(N + 3) / 4, 256, 0, stream>>>(OFF, CNT, SRCS, EXS, XH, AGG, N);

    out_kernel<<<N / 16, 256, 0, stream>>>(AGG, Wout, bias, out);
}

// Round 3
// 272.590 us; speedup vs baseline: 1.3589x; 1.3589x over previous
//
#include <hip/hip_runtime.h>

#define NEG_SLOPE 0.2f

static __device__ __forceinline__ unsigned short f2bf(float f) {
    unsigned u = __float_as_uint(f);
    unsigned r = (u + 0x7fffu + ((u >> 16) & 1u)) >> 16;   // RNE
    return (unsigned short)r;
}
static __device__ __forceinline__ float bflo(unsigned z) {
    return __uint_as_float((z & 0xffffu) << 16);
}
static __device__ __forceinline__ float bfhi(unsigned z) {
    return __uint_as_float(z & 0xffff0000u);
}

// ---- prep: Wc[k][c] = sum_m Wl[k][h*64+m]*Wout[h*64+m][c&63], h=c>>6
//      avec[k][t]: t=0,1 -> att_l heads 0,1 ; t=2,3 -> att_r heads 0,1
__global__ __launch_bounds__(256) void prep_kernel(
    const float* __restrict__ Wl, const float* __restrict__ Wout,
    const float* __restrict__ attL, const float* __restrict__ attR,
    float* __restrict__ Wc, float* __restrict__ avec)
{
    int idx = blockIdx.x * 256 + threadIdx.x;
    if (idx < 128 * 128) {
        int k = idx >> 7, c = idx & 127;
        int h = c >> 6, cc = c & 63;
        const float* wl = Wl + k * 128 + h * 64;
        const float* wo = Wout + (h * 64) * 64 + cc;
        float s = 0.f;
#pragma unroll 8
        for (int m = 0; m < 64; ++m) s += wl[m] * wo[m * 64];
        Wc[k * 128 + c] = s;
    } else if (idx < 128 * 128 + 512) {
        int r = idx - 128 * 128;
        int k = r >> 2, t = r & 3;
        int h = t & 1;
        const float* av = ((t < 2) ? attL : attR) + h * 64;
        const float* wl = Wl + k * 128 + h * 64;
        float s = 0.f;
#pragma unroll 8
        for (int m = 0; m < 64; ++m) s += wl[m] * av[m];
        avec[k * 4 + t] = s;
    }
}

// ---- zproj: Z(bf16)[N][128] = x @ Wc ; AL/AR[N][2] = x . avec ----
__global__ __launch_bounds__(256, 4) void zproj_kernel(
    const float* __restrict__ x, const float* __restrict__ Wc,
    const float* __restrict__ avec, int N,
    unsigned short* __restrict__ Z, float* __restrict__ AL, float* __restrict__ AR)
{
    __shared__ float xs[64 * 136];   // row-major, stride 136 (16B aligned rows)
    __shared__ float avs[128 * 4];
    const int tid = threadIdx.x;
    const int row0 = blockIdx.x * 64;

    const float4* x4 = (const float4*)x;
#pragma unroll
    for (int it = 0; it < 8; ++it) {
        int f4 = it * 256 + tid;           // 2048 float4 = 64 rows x 32 chunks
        int r = f4 >> 5, kq = f4 & 31;
        int rsrc = row0 + r; if (rsrc >= N) rsrc = N - 1;
        float4 v = x4[(size_t)rsrc * 32 + kq];
        *(float4*)&xs[r * 136 + kq * 4] = v;
    }
    if (tid < 128) *(float4*)&avs[tid * 4] = *(const float4*)&avec[tid * 4];
    __syncthreads();

    const int cg = tid & 31;   // cols cg*4..+3
    const int rg = tid >> 5;   // rows rg*8..+7
    const int c0 = cg * 4, r0 = rg * 8;
    float acc[8][4] = {};
    const float* wp = Wc + c0;
    for (int kc = 0; kc < 32; ++kc) {
        int k = kc * 4;
        float4 w0 = *(const float4*)&wp[(k + 0) * 128];
        float4 w1 = *(const float4*)&wp[(k + 1) * 128];
        float4 w2 = *(const float4*)&wp[(k + 2) * 128];
        float4 w3 = *(const float4*)&wp[(k + 3) * 128];
#pragma unroll
        for (int i = 0; i < 8; ++i) {
            float4 xv = *(const float4*)&xs[(r0 + i) * 136 + k];
            acc[i][0] += xv.x * w0.x + xv.y * w1.x + xv.z * w2.x + xv.w * w3.x;
            acc[i][1] += xv.x * w0.y + xv.y * w1.y + xv.z * w2.y + xv.w * w3.y;
            acc[i][2] += xv.x * w0.z + xv.y * w1.z + xv.z * w2.z + xv.w * w3.z;
            acc[i][3] += xv.x * w0.w + xv.y * w1.w + xv.z * w2.w + xv.w * w3.w;
        }
    }
#pragma unroll
    for (int i = 0; i < 8; ++i) {
        int row = row0 + r0 + i;
        if (row < N) {
            ushort4 zz;
            zz.x = f2bf(acc[i][0]); zz.y = f2bf(acc[i][1]);
            zz.z = f2bf(acc[i][2]); zz.w = f2bf(acc[i][3]);
            *(ushort4*)(Z + (size_t)row * 128 + c0) = zz;
        }
    }
    // alpha tail: one dot per thread (row = tid>>2, type = tid&3)
    {
        int row = tid >> 2, t = tid & 3;
        const float* xr = &xs[row * 136];
        float s = 0.f;
#pragma unroll 8
        for (int k = 0; k < 128; k += 4) {
            float4 xv = *(const float4*)&xr[k];
            s += xv.x * avs[(k + 0) * 4 + t] + xv.y * avs[(k + 1) * 4 + t]
               + xv.z * avs[(k + 2) * 4 + t] + xv.w * avs[(k + 3) * 4 + t];
        }
        int grow = row0 + row;
        if (grow < N) {
            if (t < 2) AL[grow * 2 + t] = s;
            else       AR[grow * 2 + (t - 2)] = s;
        }
    }
}

// ---- CSR build ----
__global__ void count_kernel(const int* __restrict__ ei, int E, int Etot,
                             int* __restrict__ cnt)
{
    int e = blockIdx.x * 256 + threadIdx.x;
    if (e >= Etot) return;
    int dst = (e < E) ? ei[E + e] : (e - E);
    atomicAdd(&cnt[dst], 1);
}

__global__ __launch_bounds__(256) void scan1(const int* __restrict__ cnt, int N,
                                             int* __restrict__ off, int* __restrict__ chs)
{
    __shared__ int s[256];
    int t = threadIdx.x, i = blockIdx.x * 256 + t;
    int v = (i < N) ? cnt[i] : 0;
    s[t] = v; __syncthreads();
#pragma unroll
    for (int o = 1; o < 256; o <<= 1) {
        int add = (t >= o) ? s[t - o] : 0;
        __syncthreads();
        s[t] += add;
        __syncthreads();
    }
    if (i < N) off[i] = s[t] - v;
    if (t == 255) chs[blockIdx.x] = s[255];
}

__global__ __launch_bounds__(256) void scan2(int* __restrict__ chs, int nb)
{
    __shared__ int s[256];
    int t = threadIdx.x;
    int v = (t < nb) ? chs[t] : 0;
    s[t] = v; __syncthreads();
#pragma unroll
    for (int o = 1; o < 256; o <<= 1) {
        int add = (t >= o) ? s[t - o] : 0;
        __syncthreads();
        s[t] += add;
        __syncthreads();
    }
    if (t < nb) chs[t] = s[t] - v;
}

__global__ void scan3(int* __restrict__ off, const int* __restrict__ chs, int N)
{
    int i = blockIdx.x * 256 + threadIdx.x;
    if (i < N) off[i] += chs[i >> 8];
}

// ---- fill: one 16B record per edge {src, ex_h0, ex_h1, 0} ----
__global__ void fill_kernel(const int* __restrict__ ei, int E, int Etot,
                            const float* __restrict__ AL, const float* __restrict__ AR,
                            int* __restrict__ off, float4* __restrict__ edg)
{
    int e = blockIdx.x * 256 + threadIdx.x;
    if (e >= Etot) return;
    int src, dst;
    if (e < E) { src = ei[e]; dst = ei[E + e]; }
    else       { src = e - E; dst = e - E; }
    float2 al = *(const float2*)&AL[src * 2];
    float2 ar = *(const float2*)&AR[dst * 2];
    float e0 = al.x + ar.x, e1 = al.y + ar.y;
    e0 = (e0 < 0.f) ? NEG_SLOPE * e0 : e0;
    e1 = (e1 < 0.f) ? NEG_SLOPE * e1 : e1;
    int pos = atomicAdd(&off[dst], 1);
    float4 rec;
    rec.x = __int_as_float(src);
    rec.y = __expf(e0);
    rec.z = __expf(e1);
    rec.w = 0.f;
    edg[pos] = rec;
}

// ---- agg: wave per node, 2 edges per iteration, fused output + bias ----
__global__ __launch_bounds__(256) void agg_kernel(
    const int* __restrict__ off, const int* __restrict__ cnt,
    const float4* __restrict__ edg, const unsigned short* __restrict__ Z,
    const float* __restrict__ bias, float* __restrict__ out, int N)
{
    int wid = threadIdx.x >> 6, lane = threadIdx.x & 63;
    int node = blockIdx.x * 4 + wid;
    if (node >= N) return;
    int end = off[node];
    int start = end - cnt[node];
    int h2 = lane >> 5;            // which of the 2 edges this half-wave handles
    int l5 = lane & 31;            // 32 lanes cover one 256B Z row (8B each)
    int head = l5 >> 4;            // lanes 0-15: head0 ch 4l.., 16-31: head1
    float a0 = 0.f, a1 = 0.f, a2 = 0.f, a3 = 0.f, ws = 0.f;
    for (int e = start; e < end; e += 2) {
        float4 r0 = edg[e];
        float4 r1 = (e + 1 < end) ? edg[e + 1] : make_float4(r0.x, 0.f, 0.f, 0.f);
        float4 rc = h2 ? r1 : r0;
        int j = __float_as_int(rc.x);
        float w = head ? rc.z : rc.y;
        uint2 zz = *(const uint2*)(Z + (size_t)j * 128 + l5 * 4);
        a0 += w * bflo(zz.x); a1 += w * bfhi(zz.x);
        a2 += w * bflo(zz.y); a3 += w * bfhi(zz.y);
        ws += w;
    }
    // combine the two edge-halves (same node, same channels)
    a0 += __shfl_xor(a0, 32); a1 += __shfl_xor(a1, 32);
    a2 += __shfl_xor(a2, 32); a3 += __shfl_xor(a3, 32);
    ws += __shfl_xor(ws, 32);
    float inv = 1.f / (ws + 1e-16f);
    a0 *= inv; a1 *= inv; a2 *= inv; a3 *= inv;
    // add the other head's contribution (channels match across the 16-lane split)
    a0 += __shfl_xor(a0, 16); a1 += __shfl_xor(a1, 16);
    a2 += __shfl_xor(a2, 16); a3 += __shfl_xor(a3, 16);
    if (lane < 16) {
        float4 bv = *(const float4*)&bias[lane * 4];
        float4 o = make_float4(a0 + bv.x, a1 + bv.y, a2 + bv.z, a3 + bv.w);
        *(float4*)&out[(size_t)node * 64 + lane * 4] = o;
    }
}

// ---------------- launch ----------------
extern "C" void kernel_launch(void* const* d_in, const int* in_sizes, int n_in,
                              void* d_out, int out_size, void* d_ws, size_t ws_size,
                              hipStream_t stream)
{
    const float* x    = (const float*)d_in[0];
    const int*   ei   = (const int*)d_in[1];
    const float* Wl   = (const float*)d_in[2];
    const float* attL = (const float*)d_in[3];
    const float* attR = (const float*)d_in[4];
    const float* Wout = (const float*)d_in[5];
    const float* bias = (const float*)d_in[6];
    float* out = (float*)d_out;

    const int N = in_sizes[0] / 128;   // 50000
    const int E = in_sizes[1] / 2;     // 800000
    const int Etot = E + N;

    char* ws = (char*)d_ws;
    size_t o = 0;
    auto alloc = [&](size_t bytes) {
        void* p = ws + o; o += (bytes + 255) & ~(size_t)255; return p;
    };
    float*          Wc   = (float*)alloc(128 * 128 * 4);
    float*          AV   = (float*)alloc(128 * 4 * 4);
    unsigned short* Z    = (unsigned short*)alloc((size_t)N * 128 * 2);  // 12.8 MB
    float*          AL   = (float*)alloc((size_t)N * 2 * 4);
    float*          AR   = (float*)alloc((size_t)N * 2 * 4);
    int*            CNT  = (int*)alloc((size_t)N * 4);
    int*            OFF  = (int*)alloc((size_t)N * 4);
    int*            CHS  = (int*)alloc(256 * 4);
    float4*         EDG  = (float4*)alloc((size_t)Etot * 16);            // 13.6 MB

    hipMemsetAsync(CNT, 0, (size_t)N * 4, stream);

    prep_kernel<<<66, 256, 0, stream>>>(Wl, Wout, attL, attR, Wc, AV);
    zproj_kernel<<<(N + 63) / 64, 256, 0, stream>>>(x, Wc, AV, N, Z, AL, AR);

    int eb = (Etot + 255) / 256;
    count_kernel<<<eb, 256, 0, stream>>>(ei, E, Etot, CNT);
    int nb = (N + 255) / 256;
    scan1<<<nb, 256, 0, stream>>>(CNT, N, OFF, CHS);
    scan2<<<1, 256, 0, stream>>>(CHS, nb);
    scan3<<<nb, 256, 0, stream>>>(OFF, CHS, N);
    fill_kernel<<<eb, 256, 0, stream>>>(ei, E, Etot, AL, AR, OFF, EDG);

    agg_kernel<<<(N + 3) / 4, 256, 0, stream>>>(OFF, CNT, EDG, Z, bias, out, N);
}

// Round 4
// 231.002 us; speedup vs baseline: 1.6036x; 1.1800x over previous
//
#include <hip/hip_runtime.h>
#include <hip/hip_fp16.h>

#define NEG_SLOPE 0.2f

static __device__ __forceinline__ unsigned short f2bf(float f) {
    unsigned u = __float_as_uint(f);
    unsigned r = (u + 0x7fffu + ((u >> 16) & 1u)) >> 16;   // RNE
    return (unsigned short)r;
}
static __device__ __forceinline__ float bflo(unsigned z) {
    return __uint_as_float((z & 0xffffu) << 16);
}
static __device__ __forceinline__ float bfhi(unsigned z) {
    return __uint_as_float(z & 0xffff0000u);
}

#define PREP_B 66   // blocks for prep part (128*128+512 = 16896 threads)

// ---- K1: prep (Wc, avec)  ||  count (degree histogram) ----
__global__ __launch_bounds__(256) void prep_count_kernel(
    const float* __restrict__ Wl, const float* __restrict__ Wout,
    const float* __restrict__ attL, const float* __restrict__ attR,
    float* __restrict__ Wc, float* __restrict__ avec,
    const int* __restrict__ ei, int E, int Etot, int* __restrict__ cnt)
{
    int bid = blockIdx.x;
    if (bid < PREP_B) {
        int idx = bid * 256 + threadIdx.x;
        if (idx < 128 * 128) {
            int k = idx >> 7, c = idx & 127;
            int h = c >> 6, cc = c & 63;
            const float* wl = Wl + k * 128 + h * 64;
            const float* wo = Wout + (h * 64) * 64 + cc;
            float s = 0.f;
#pragma unroll 8
            for (int m = 0; m < 64; ++m) s += wl[m] * wo[m * 64];
            Wc[k * 128 + c] = s;
        } else if (idx < 128 * 128 + 512) {
            int r = idx - 128 * 128;
            int k = r >> 2, t = r & 3;
            int h = t & 1;
            const float* av = ((t < 2) ? attL : attR) + h * 64;
            const float* wl = Wl + k * 128 + h * 64;
            float s = 0.f;
#pragma unroll 8
            for (int m = 0; m < 64; ++m) s += wl[m] * av[m];
            avec[k * 4 + t] = s;
        }
    } else {
        int e = (bid - PREP_B) * 256 + threadIdx.x;
        if (e >= Etot) return;
        int dst = (e < E) ? ei[E + e] : (e - E);
        atomicAdd(&cnt[dst], 1);
    }
}

// ---- K2: zproj (Z bf16, AL/AR)  ||  scan1 (per-chunk exclusive scan) ----
__global__ __launch_bounds__(256, 4) void zproj_scan_kernel(
    const float* __restrict__ x, const float* __restrict__ Wc,
    const float* __restrict__ avec, int N, int ZB,
    unsigned short* __restrict__ Z, float* __restrict__ AL, float* __restrict__ AR,
    const int* __restrict__ cnt, int* __restrict__ off, int* __restrict__ chs)
{
    __shared__ float xs[64 * 136];   // zproj x tile; scan1 reuses as int[256]
    __shared__ float avs[128 * 4];
    const int tid = threadIdx.x;

    if ((int)blockIdx.x >= ZB) {
        // ----- scan1 -----
        int blk = blockIdx.x - ZB;
        int* s = (int*)xs;
        int i = blk * 256 + tid;
        int v = (i < N) ? cnt[i] : 0;
        s[tid] = v; __syncthreads();
#pragma unroll
        for (int o = 1; o < 256; o <<= 1) {
            int add = (tid >= o) ? s[tid - o] : 0;
            __syncthreads();
            s[tid] += add;
            __syncthreads();
        }
        if (i < N) off[i] = s[tid] - v;     // exclusive within chunk
        if (tid == 255) chs[blk] = s[255];  // chunk total
        return;
    }

    // ----- zproj -----
    const int row0 = blockIdx.x * 64;
    const float4* x4 = (const float4*)x;
#pragma unroll
    for (int it = 0; it < 8; ++it) {
        int f4 = it * 256 + tid;           // 2048 float4 = 64 rows x 32 chunks
        int r = f4 >> 5, kq = f4 & 31;
        int rsrc = row0 + r; if (rsrc >= N) rsrc = N - 1;
        float4 v = x4[(size_t)rsrc * 32 + kq];
        *(float4*)&xs[r * 136 + kq * 4] = v;
    }
    if (tid < 128) *(float4*)&avs[tid * 4] = *(const float4*)&avec[tid * 4];
    __syncthreads();

    const int cg = tid & 31;   // cols cg*4..+3
    const int rg = tid >> 5;   // rows rg*8..+7
    const int c0 = cg * 4, r0 = rg * 8;
    float acc[8][4] = {};
    const float* wp = Wc + c0;
    for (int kc = 0; kc < 32; ++kc) {
        int k = kc * 4;
        float4 w0 = *(const float4*)&wp[(k + 0) * 128];
        float4 w1 = *(const float4*)&wp[(k + 1) * 128];
        float4 w2 = *(const float4*)&wp[(k + 2) * 128];
        float4 w3 = *(const float4*)&wp[(k + 3) * 128];
#pragma unroll
        for (int i = 0; i < 8; ++i) {
            float4 xv = *(const float4*)&xs[(r0 + i) * 136 + k];
            acc[i][0] += xv.x * w0.x + xv.y * w1.x + xv.z * w2.x + xv.w * w3.x;
            acc[i][1] += xv.x * w0.y + xv.y * w1.y + xv.z * w2.y + xv.w * w3.y;
            acc[i][2] += xv.x * w0.z + xv.y * w1.z + xv.z * w2.z + xv.w * w3.z;
            acc[i][3] += xv.x * w0.w + xv.y * w1.w + xv.z * w2.w + xv.w * w3.w;
        }
    }
#pragma unroll
    for (int i = 0; i < 8; ++i) {
        int row = row0 + r0 + i;
        if (row < N) {
            ushort4 zz;
            zz.x = f2bf(acc[i][0]); zz.y = f2bf(acc[i][1]);
            zz.z = f2bf(acc[i][2]); zz.w = f2bf(acc[i][3]);
            *(ushort4*)(Z + (size_t)row * 128 + c0) = zz;
        }
    }
    // alpha tail: one dot per thread (row = tid>>2, type = tid&3)
    {
        int row = tid >> 2, t = tid & 3;
        const float* xr = &xs[row * 136];
        float s = 0.f;
#pragma unroll 8
        for (int k = 0; k < 128; k += 4) {
            float4 xv = *(const float4*)&xr[k];
            s += xv.x * avs[(k + 0) * 4 + t] + xv.y * avs[(k + 1) * 4 + t]
               + xv.z * avs[(k + 2) * 4 + t] + xv.w * avs[(k + 3) * 4 + t];
        }
        int grow = row0 + row;
        if (grow < N) {
            if (t < 2) AL[grow * 2 + t] = s;
            else       AR[grow * 2 + (t - 2)] = s;
        }
    }
}

// ---- K3: scan of chunk totals (nb <= 256, single block) ----
__global__ __launch_bounds__(256) void scan2(int* __restrict__ chs, int nb)
{
    __shared__ int s[256];
    int t = threadIdx.x;
    int v = (t < nb) ? chs[t] : 0;
    s[t] = v; __syncthreads();
#pragma unroll
    for (int o = 1; o < 256; o <<= 1) {
        int add = (t >= o) ? s[t - o] : 0;
        __syncthreads();
        s[t] += add;
        __syncthreads();
    }
    if (t < nb) chs[t] = s[t] - v;   // exclusive chunk offsets
}

// ---- K4: fill CSR records {src, half2(ex0,ex1)} = 8B ----
__global__ void fill_kernel(const int* __restrict__ ei, int E, int Etot,
                            const float* __restrict__ AL, const float* __restrict__ AR,
                            int* __restrict__ off, const int* __restrict__ chs,
                            uint2* __restrict__ edg)
{
    int e = blockIdx.x * 256 + threadIdx.x;
    if (e >= Etot) return;
    int src, dst;
    if (e < E) { src = ei[e]; dst = ei[E + e]; }
    else       { src = e - E; dst = e - E; }
    float2 al = *(const float2*)&AL[src * 2];
    float2 ar = *(const float2*)&AR[dst * 2];
    float e0 = al.x + ar.x, e1 = al.y + ar.y;
    e0 = (e0 < 0.f) ? NEG_SLOPE * e0 : e0;
    e1 = (e1 < 0.f) ? NEG_SLOPE * e1 : e1;
    int pos = atomicAdd(&off[dst], 1) + chs[dst >> 8];
    __half2 hh = __floats2half2_rn(__expf(e0), __expf(e1));
    uint2 rec;
    rec.x = (unsigned)src;
    rec.y = *(unsigned*)&hh;
    edg[pos] = rec;
}

// ---- K5: agg — wave/node, 16-lane groups, 4 edges in flight ----
__global__ __launch_bounds__(256) void agg_kernel(
    const int* __restrict__ off, const int* __restrict__ chs,
    const int* __restrict__ cnt, const uint2* __restrict__ edg,
    const unsigned short* __restrict__ Z, const float* __restrict__ bias,
    float* __restrict__ out, int N)
{
    int wid = threadIdx.x >> 6, lane = threadIdx.x & 63;
    int node = blockIdx.x * 4 + wid;
    if (node >= N) return;
    int base = chs[node >> 8];
    int end  = base + off[node];     // off = local start+deg after fill
    int start = end - cnt[node];
    int g  = lane >> 4;              // edge slot 0..3
    int l4 = lane & 15;              // 16B chunk of the 256B Z row
    int h  = l4 >> 3;                // head owning these channels
    float a[8] = {};
    float ws = 0.f;
    uint2 rec = make_uint2(0u, 0u);
    if (start + g < end) rec = edg[start + g];
    for (int e = start; e < end; e += 4) {
        uint2 nrec = make_uint2(0u, 0u);
        int ne = e + 4 + g;
        if (ne < end) nrec = edg[ne];
        int j = (int)rec.x;
        unsigned hv = h ? (rec.y >> 16) : (rec.y & 0xffffu);
        float w = __half2float(__ushort_as_half((unsigned short)hv));
        uint4 zz = *(const uint4*)(Z + (size_t)j * 128 + l4 * 8);
        a[0] += w * bflo(zz.x); a[1] += w * bfhi(zz.x);
        a[2] += w * bflo(zz.y); a[3] += w * bfhi(zz.y);
        a[4] += w * bflo(zz.z); a[5] += w * bfhi(zz.z);
        a[6] += w * bflo(zz.w); a[7] += w * bfhi(zz.w);
        ws += w;
        rec = nrec;
    }
#pragma unroll
    for (int i = 0; i < 8; ++i) {
        a[i] += __shfl_xor(a[i], 16);
        a[i] += __shfl_xor(a[i], 32);
    }
    ws += __shfl_xor(ws, 16);
    ws += __shfl_xor(ws, 32);
    float inv = 1.f / (ws + 1e-16f);
#pragma unroll
    for (int i = 0; i < 8; ++i) a[i] *= inv;
    // head combine: lane m (head0 ch 8m..) pairs with lane m+8 (head1 same out ch)
#pragma unroll
    for (int i = 0; i < 8; ++i) a[i] += __shfl_xor(a[i], 8);
    if (lane < 8) {
        float4 b0 = *(const float4*)&bias[lane * 8];
        float4 b1 = *(const float4*)&bias[lane * 8 + 4];
        float4 o0 = make_float4(a[0] + b0.x, a[1] + b0.y, a[2] + b0.z, a[3] + b0.w);
        float4 o1 = make_float4(a[4] + b1.x, a[5] + b1.y, a[6] + b1.z, a[7] + b1.w);
        *(float4*)&out[(size_t)node * 64 + lane * 8] = o0;
        *(float4*)&out[(size_t)node * 64 + lane * 8 + 4] = o1;
    }
}

// ---------------- launch ----------------
extern "C" void kernel_launch(void* const* d_in, const int* in_sizes, int n_in,
                              void* d_out, int out_size, void* d_ws, size_t ws_size,
                              hipStream_t stream)
{
    const float* x    = (const float*)d_in[0];
    const int*   ei   = (const int*)d_in[1];
    const float* Wl   = (const float*)d_in[2];
    const float* attL = (const float*)d_in[3];
    const float* attR = (const float*)d_in[4];
    const float* Wout = (const float*)d_in[5];
    const float* bias = (const float*)d_in[6];
    float* out = (float*)d_out;

    const int N = in_sizes[0] / 128;   // 50000
    const int E = in_sizes[1] / 2;     // 800000
    const int Etot = E + N;

    char* ws = (char*)d_ws;
    size_t o = 0;
    auto alloc = [&](size_t bytes) {
        void* p = ws + o; o += (bytes + 255) & ~(size_t)255; return p;
    };
    float*          Wc   = (float*)alloc(128 * 128 * 4);
    float*          AV   = (float*)alloc(128 * 4 * 4);
    unsigned short* Z    = (unsigned short*)alloc((size_t)N * 128 * 2);  // 12.8 MB
    float*          AL   = (float*)alloc((size_t)N * 2 * 4);
    float*          AR   = (float*)alloc((size_t)N * 2 * 4);
    int*            CNT  = (int*)alloc((size_t)N * 4);
    int*            OFF  = (int*)alloc((size_t)N * 4);
    int*            CHS  = (int*)alloc(256 * 4);
    uint2*          EDG  = (uint2*)alloc((size_t)Etot * 8);              // 6.8 MB

    hipMemsetAsync(CNT, 0, (size_t)N * 4, stream);

    int eb = (Etot + 255) / 256;
    int nb = (N + 255) / 256;          // 196
    int ZB = (N + 63) / 64;            // 782

    prep_count_kernel<<<PREP_B + eb, 256, 0, stream>>>(Wl, Wout, attL, attR,
                                                       Wc, AV, ei, E, Etot, CNT);
    zproj_scan_kernel<<<ZB + nb, 256, 0, stream>>>(x, Wc, AV, N, ZB,
                                                   Z, AL, AR, CNT, OFF, CHS);
    scan2<<<1, 256, 0, stream>>>(CHS, nb);
    fill_kernel<<<eb, 256, 0, stream>>>(ei, E, Etot, AL, AR, OFF, CHS, EDG);
    agg_kernel<<<(N + 3) / 4, 256, 0, stream>>>(OFF, CHS, CNT, EDG, Z, bias, out, N);
}